// Round 1
// baseline (5789.825 us; speedup 1.0000x reference)
//
#include <hip/hip_runtime.h>
#include <cstdint>
#include <cstddef>

#define B_ 64
#define T_ 2048
#define I_ 256
#define H_ 256
#define G_ 768   // 3*H

typedef _Float16 h2v __attribute__((ext_vector_type(2)));
typedef _Float16 v8h __attribute__((ext_vector_type(8)));
typedef float    v4f __attribute__((ext_vector_type(4)));

union U32h { uint32_t u; h2v h; };

__device__ __forceinline__ h2v asH(uint32_t u) { U32h t; t.u = u; return t.h; }

// ---------------------------------------------------------------------------
// prep: swizzle W_hh fp32 [768][256] row-major -> f16-pair layout
// Wsw[(g*128 + p)*256 + j] = half2(W_hh[g*256+j][2p], W_hh[g*256+j][2p+1])
// so the recurrent kernel's per-thread weight loads are fully coalesced.
// ---------------------------------------------------------------------------
__global__ void prep_whh(const float* __restrict__ Whh, uint32_t* __restrict__ Wsw) {
    int row = blockIdx.x;      // 0..767
    int p   = threadIdx.x;     // 0..127
    int g = row >> 8, j = row & 255;
    float a = Whh[row * 256 + 2 * p];
    float b = Whh[row * 256 + 2 * p + 1];
    U32h u; u.h = h2v{(_Float16)a, (_Float16)b};
    Wsw[(g * 128 + p) * 256 + j] = u.u;
}

// ---------------------------------------------------------------------------
// gi GEMM: gi[t_local*64 + b][n] = sum_k x[b][t0+t_local][k] * W_ih[n][k] + b_ih[n]
// One block per (t_local, n-half). Tile: M=64 (all batches of one t) x N=384, K=256.
// MFMA f32_16x16x32_f16. LDS rows padded to 56 halves (112B: 16B-aligned reads,
// 2-way-max bank aliasing which is free).
// ---------------------------------------------------------------------------
#define LDA 56
#define LDB 56

__launch_bounds__(256, 2)
__global__ void gemm_gi(const float* __restrict__ x, const float* __restrict__ Wih,
                        const float* __restrict__ bih, _Float16* __restrict__ gi,
                        int t0) {
    __shared__ __align__(16) _Float16 As[64 * LDA];
    __shared__ __align__(16) _Float16 Bs[384 * LDB];
    int tid  = threadIdx.x;
    int t    = t0 + blockIdx.x;
    int n0   = blockIdx.y * 384;
    int lane = tid & 63, wave = tid >> 6;
    int quad = lane >> 4, r16 = lane & 15;

    v4f acc[24];
#pragma unroll
    for (int i = 0; i < 24; ++i) acc[i] = v4f{0.f, 0.f, 0.f, 0.f};

    for (int ki = 0; ki < 8; ++ki) {
        int k0 = ki * 32;
        __syncthreads();
        // stage A: 64 batch rows x 32 k (f32 -> f16)
#pragma unroll
        for (int s = 0; s < 2; ++s) {
            int slot = tid + s * 256;
            int row = slot >> 3;      // batch b
            int part = slot & 7;
            const float* xp = x + ((size_t)row * T_ + t) * I_ + k0 + part * 4;
            float4 v = *(const float4*)xp;
            U32h u0, u1;
            u0.h = h2v{(_Float16)v.x, (_Float16)v.y};
            u1.h = h2v{(_Float16)v.z, (_Float16)v.w};
            uint32_t* dst = (uint32_t*)&As[row * LDA + part * 4];
            dst[0] = u0.u; dst[1] = u1.u;
        }
        // stage B: 384 W_ih rows x 32 k
#pragma unroll
        for (int s = 0; s < 12; ++s) {
            int slot = tid + s * 256;
            int row = slot >> 3;
            int part = slot & 7;
            const float* wp = Wih + (size_t)(n0 + row) * I_ + k0 + part * 4;
            float4 v = *(const float4*)wp;
            U32h u0, u1;
            u0.h = h2v{(_Float16)v.x, (_Float16)v.y};
            u1.h = h2v{(_Float16)v.z, (_Float16)v.w};
            uint32_t* dst = (uint32_t*)&Bs[row * LDB + part * 4];
            dst[0] = u0.u; dst[1] = u1.u;
        }
        __syncthreads();
        // A-frag: A[m = lane&15][k = quad*8 + j]
        v8h af = *(const v8h*)&As[(wave * 16 + r16) * LDA + quad * 8];
#pragma unroll
        for (int nt = 0; nt < 24; ++nt) {
            v8h bf = *(const v8h*)&Bs[(nt * 16 + r16) * LDB + quad * 8];
            acc[nt] = __builtin_amdgcn_mfma_f32_16x16x32_f16(af, bf, acc[nt], 0, 0, 0);
        }
    }
    // epilogue: D col = lane&15, row = quad*4 + reg (within wave's 16-row block)
#pragma unroll
    for (int nt = 0; nt < 24; ++nt) {
        int n = n0 + nt * 16 + r16;
        float bias = bih[n];
#pragma unroll
        for (int reg = 0; reg < 4; ++reg) {
            int m = wave * 16 + quad * 4 + reg;   // batch index
            size_t off = ((size_t)blockIdx.x * 64 + m) * G_ + n;
            gi[off] = (_Float16)(acc[nt][reg] + bias);
        }
    }
}

// ---------------------------------------------------------------------------
// Recurrent kernel: one block per batch element, persistent over len steps.
// Thread j owns columns j of all three gates; W_hh rows (j, 256+j, 512+j)
// live in 384 VGPRs as f16 pairs. h broadcast through LDS (f16, dbuf),
// h itself carried in an fp32 register. One __syncthreads per step.
// ---------------------------------------------------------------------------
__launch_bounds__(256, 1)
__global__ void rec_step(const uint32_t* __restrict__ Wsw, const float* __restrict__ bhh,
                         const _Float16* __restrict__ gi, const float* __restrict__ h_init,
                         float* __restrict__ out, float* __restrict__ hN,
                         float* __restrict__ h_carry, int t0, int len) {
    __shared__ __align__(16) _Float16 hb[2][256];
    int b = blockIdx.x, j = threadIdx.x;

    uint32_t w0[128], w1[128], w2[128];
#pragma unroll
    for (int p = 0; p < 128; ++p) w0[p] = Wsw[(0 * 128 + p) * 256 + j];
#pragma unroll
    for (int p = 0; p < 128; ++p) w1[p] = Wsw[(128 + p) * 256 + j];
#pragma unroll
    for (int p = 0; p < 128; ++p) w2[p] = Wsw[(256 + p) * 256 + j];

    float bh0 = bhh[j], bh1 = bhh[256 + j], bh2 = bhh[512 + j];
    float hprev = h_init[b * 256 + j];
    hb[0][j] = (_Float16)hprev;

    const _Float16* gp = gi + (size_t)b * G_ + j;
    // prefetch gi for t = 0
    float g0 = (float)gp[0], g1 = (float)gp[256], g2 = (float)gp[512];

    float* outp = out + (size_t)b * T_ * H_ + (size_t)t0 * H_ + j;
    __syncthreads();

    int cur = 0;
    for (int t = 0; t < len; ++t) {
        // prefetch next step's gi (HBM latency ~900cy ≈ one step of compute)
        float p0 = 0.f, p1 = 0.f, p2 = 0.f;
        if (t + 1 < len) {
            const _Float16* gq = gp + (size_t)(t + 1) * B_ * G_;
            p0 = (float)gq[0]; p1 = (float)gq[256]; p2 = (float)gq[512];
        }

        float a0 = bh0, a1 = bh1, a2 = bh2;
        const float4* hv4 = (const float4*)&hb[cur][0];   // wave-uniform: LDS broadcast
#pragma unroll
        for (int kk = 0; kk < 32; ++kk) {
            float4 hv = hv4[kk];
            h2v h0 = asH(__float_as_uint(hv.x));
            h2v h1 = asH(__float_as_uint(hv.y));
            h2v h2 = asH(__float_as_uint(hv.z));
            h2v h3 = asH(__float_as_uint(hv.w));
            a0 = __builtin_amdgcn_fdot2(asH(w0[kk * 4 + 0]), h0, a0, false);
            a1 = __builtin_amdgcn_fdot2(asH(w1[kk * 4 + 0]), h0, a1, false);
            a2 = __builtin_amdgcn_fdot2(asH(w2[kk * 4 + 0]), h0, a2, false);
            a0 = __builtin_amdgcn_fdot2(asH(w0[kk * 4 + 1]), h1, a0, false);
            a1 = __builtin_amdgcn_fdot2(asH(w1[kk * 4 + 1]), h1, a1, false);
            a2 = __builtin_amdgcn_fdot2(asH(w2[kk * 4 + 1]), h1, a2, false);
            a0 = __builtin_amdgcn_fdot2(asH(w0[kk * 4 + 2]), h2, a0, false);
            a1 = __builtin_amdgcn_fdot2(asH(w1[kk * 4 + 2]), h2, a1, false);
            a2 = __builtin_amdgcn_fdot2(asH(w2[kk * 4 + 2]), h2, a2, false);
            a0 = __builtin_amdgcn_fdot2(asH(w0[kk * 4 + 3]), h3, a0, false);
            a1 = __builtin_amdgcn_fdot2(asH(w1[kk * 4 + 3]), h3, a1, false);
            a2 = __builtin_amdgcn_fdot2(asH(w2[kk * 4 + 3]), h3, a2, false);
        }
        // gates: chunk0 = reset, chunk1 = candidate, chunk2 = update
        float r = 1.f / (1.f + __expf(-(g0 + a0)));
        float u = 1.f / (1.f + __expf(-(g2 + a2)));
        float carg = g1 + r * a1;
        carg = fminf(fmaxf(carg, -20.f), 20.f);    // avoid inf/inf in tanh
        float e2 = __expf(2.f * carg);
        float n = (e2 - 1.f) / (e2 + 1.f);
        float hnew = hprev + u * (n - hprev);      // (1-u)h + u*n

        outp[(size_t)t * H_] = hnew;
        hb[cur ^ 1][j] = (_Float16)hnew;
        hprev = hnew;
        g0 = p0; g1 = p1; g2 = p2;
        __syncthreads();
        cur ^= 1;
    }
    h_carry[b * 256 + j] = hprev;
    if (t0 + len == T_) hN[b * 256 + j] = hprev;
}

// ---------------------------------------------------------------------------
extern "C" void kernel_launch(void* const* d_in, const int* in_sizes, int n_in,
                              void* d_out, int out_size, void* d_ws, size_t ws_size,
                              hipStream_t stream) {
    const float* x   = (const float*)d_in[0];
    const float* h0  = (const float*)d_in[1];
    const float* Wih = (const float*)d_in[2];
    const float* bih = (const float*)d_in[3];
    const float* Whh = (const float*)d_in[4];
    const float* bhh = (const float*)d_in[5];
    float* out = (float*)d_out;
    float* hN  = out + (size_t)B_ * T_ * H_;

    char* ws = (char*)d_ws;
    float*    h_carry = (float*)ws;                       // 65536 B
    uint32_t* Wsw     = (uint32_t*)(ws + 65536);          // 393216 B
    _Float16* gi      = (_Float16*)(ws + 65536 + 393216);

    const size_t head = 65536 + 393216;
    const size_t per_t = (size_t)B_ * G_ * sizeof(_Float16);  // 98304 B
    size_t avail = (ws_size > head) ? (ws_size - head) : 0;
    int tc = (int)(avail / per_t);
    if (tc > T_) tc = T_;
    if (tc < 1)  tc = 1;
    int nch = (T_ + tc - 1) / tc;
    tc = (T_ + nch - 1) / nch;   // balance chunk sizes

    hipLaunchKernelGGL(prep_whh, dim3(768), dim3(128), 0, stream, Whh, Wsw);
    for (int t0 = 0; t0 < T_; t0 += tc) {
        int len = (T_ - t0 < tc) ? (T_ - t0) : tc;
        hipLaunchKernelGGL(gemm_gi, dim3(len, 2), dim3(256), 0, stream,
                           x, Wih, bih, gi, t0);
        const float* hi = (t0 == 0) ? h0 : h_carry;
        hipLaunchKernelGGL(rec_step, dim3(64), dim3(256), 0, stream,
                           Wsw, bhh, gi, hi, out, hN, h_carry, t0, len);
    }
}

// Round 2
// 2970.135 us; speedup vs baseline: 1.9493x; 1.9493x over previous
//
#include <hip/hip_runtime.h>
#include <cstdint>
#include <cstddef>

#define B_ 64
#define T_ 2048
#define I_ 256
#define H_ 256
#define G_ 768   // 3*H

typedef _Float16 h2v __attribute__((ext_vector_type(2)));
typedef _Float16 v8h __attribute__((ext_vector_type(8)));
typedef float    v4f __attribute__((ext_vector_type(4)));
typedef uint32_t u32x4 __attribute__((ext_vector_type(4)));

union U32h { uint32_t u; h2v h; };
__device__ __forceinline__ h2v asH(uint32_t u) { U32h t; t.u = u; return t.h; }

// ---------------------------------------------------------------------------
// prep: Whh fp32 [768][256] -> per-thread-contiguous f16-pair layout.
// Wprep[((g*2 + half)*256 + j)*64 + p] = pair(Whh[g*256+j][half*128+2p], [.. +1])
// Thread (j, half) of rec_step then loads 16 dwordx4 per gate, fully dense.
// ---------------------------------------------------------------------------
__global__ void prep_whh2(const float* __restrict__ Whh, uint32_t* __restrict__ Wprep) {
    int j = threadIdx.x;           // 0..255
    int gh = blockIdx.x;           // 0..5 = g*2 + half
    int g = gh >> 1, half = gh & 1;
    const float* src = Whh + (size_t)(g * 256 + j) * 256 + half * 128;
    uint32_t* dst = Wprep + ((size_t)gh * 256 + j) * 64;
    for (int p = 0; p < 64; ++p) {
        U32h u; u.h = h2v{(_Float16)src[2 * p], (_Float16)src[2 * p + 1]};
        dst[p] = u.u;
    }
}

// ---------------------------------------------------------------------------
// gi GEMM (unchanged from round 1): gi[t_local*64 + b][n]
// ---------------------------------------------------------------------------
#define LDA 56
#define LDB 56

__launch_bounds__(256, 2)
__global__ void gemm_gi(const float* __restrict__ x, const float* __restrict__ Wih,
                        const float* __restrict__ bih, _Float16* __restrict__ gi,
                        int t0) {
    __shared__ __align__(16) _Float16 As[64 * LDA];
    __shared__ __align__(16) _Float16 Bs[384 * LDB];
    int tid  = threadIdx.x;
    int t    = t0 + blockIdx.x;
    int n0   = blockIdx.y * 384;
    int lane = tid & 63, wave = tid >> 6;
    int quad = lane >> 4, r16 = lane & 15;

    v4f acc[24];
#pragma unroll
    for (int i = 0; i < 24; ++i) acc[i] = v4f{0.f, 0.f, 0.f, 0.f};

    for (int ki = 0; ki < 8; ++ki) {
        int k0 = ki * 32;
        __syncthreads();
#pragma unroll
        for (int s = 0; s < 2; ++s) {
            int slot = tid + s * 256;
            int row = slot >> 3;
            int part = slot & 7;
            const float* xp = x + ((size_t)row * T_ + t) * I_ + k0 + part * 4;
            float4 v = *(const float4*)xp;
            U32h u0, u1;
            u0.h = h2v{(_Float16)v.x, (_Float16)v.y};
            u1.h = h2v{(_Float16)v.z, (_Float16)v.w};
            uint32_t* dst = (uint32_t*)&As[row * LDA + part * 4];
            dst[0] = u0.u; dst[1] = u1.u;
        }
#pragma unroll
        for (int s = 0; s < 12; ++s) {
            int slot = tid + s * 256;
            int row = slot >> 3;
            int part = slot & 7;
            const float* wp = Wih + (size_t)(n0 + row) * I_ + k0 + part * 4;
            float4 v = *(const float4*)wp;
            U32h u0, u1;
            u0.h = h2v{(_Float16)v.x, (_Float16)v.y};
            u1.h = h2v{(_Float16)v.z, (_Float16)v.w};
            uint32_t* dst = (uint32_t*)&Bs[row * LDB + part * 4];
            dst[0] = u0.u; dst[1] = u1.u;
        }
        __syncthreads();
        v8h af = *(const v8h*)&As[(wave * 16 + r16) * LDA + quad * 8];
#pragma unroll
        for (int nt = 0; nt < 24; ++nt) {
            v8h bf = *(const v8h*)&Bs[(nt * 16 + r16) * LDB + quad * 8];
            acc[nt] = __builtin_amdgcn_mfma_f32_16x16x32_f16(af, bf, acc[nt], 0, 0, 0);
        }
    }
#pragma unroll
    for (int nt = 0; nt < 24; ++nt) {
        int n = n0 + nt * 16 + r16;
        float bias = bih[n];
#pragma unroll
        for (int reg = 0; reg < 4; ++reg) {
            int m = wave * 16 + quad * 4 + reg;
            size_t off = ((size_t)blockIdx.x * 64 + m) * G_ + n;
            gi[off] = (_Float16)(acc[nt][reg] + bias);
        }
    }
}

// ---------------------------------------------------------------------------
// Recurrent kernel v2: one block of 512 threads per batch element.
// Thread (j = tid&255, half = tid>>8) computes half-dots (k in
// [half*128, half*128+128)) for gates 0..2 of column j. Weights: 48 uint4
// = 192 VGPRs per thread (SROA-friendly small arrays). Partials reduced
// via LDS; threads j<256 do gate math + h update. 2 barriers/step.
// ---------------------------------------------------------------------------
__launch_bounds__(512, 2)
__global__ void rec_step(const uint32_t* __restrict__ Wprep, const float* __restrict__ bhh,
                         const _Float16* __restrict__ gi, const float* __restrict__ h_init,
                         float* __restrict__ out, float* __restrict__ hN,
                         float* __restrict__ h_carry, int t0, int len) {
    __shared__ __align__(16) _Float16 hb[2][256];
    __shared__ float part[2][3][256];   // [half][gate][j]

    int b = blockIdx.x;
    int tid = threadIdx.x;
    int j = tid & 255, half = tid >> 8;

    // ---- load weights into registers: 3 x 16 uint4 ----
    const u32x4* wp0 = (const u32x4*)(Wprep + ((size_t)(0 * 2 + half) * 256 + j) * 64);
    const u32x4* wp1 = (const u32x4*)(Wprep + ((size_t)(1 * 2 + half) * 256 + j) * 64);
    const u32x4* wp2 = (const u32x4*)(Wprep + ((size_t)(2 * 2 + half) * 256 + j) * 64);
    u32x4 wq0[16], wq1[16], wq2[16];
#pragma unroll
    for (int p = 0; p < 16; ++p) wq0[p] = wp0[p];
#pragma unroll
    for (int p = 0; p < 16; ++p) wq1[p] = wp1[p];
#pragma unroll
    for (int p = 0; p < 16; ++p) wq2[p] = wp2[p];

    // ---- pointwise-thread state (tid < 256) ----
    float bh0 = 0.f, bh1 = 0.f, bh2 = 0.f, hprev = 0.f;
    float g0 = 0.f, g1 = 0.f, g2 = 0.f;
    const _Float16* gp = gi + (size_t)b * G_ + j;
    float* outp = out + (size_t)b * T_ * H_ + (size_t)t0 * H_ + j;
    if (tid < 256) {
        bh0 = bhh[j]; bh1 = bhh[256 + j]; bh2 = bhh[512 + j];
        hprev = h_init[b * 256 + j];
        hb[0][j] = (_Float16)hprev;
        g0 = (float)gp[0]; g1 = (float)gp[256]; g2 = (float)gp[512];
    }
    __syncthreads();

    int cur = 0;
    for (int t = 0; t < len; ++t) {
        // prefetch next step's gi (consumed after the dot phase)
        float p0 = 0.f, p1 = 0.f, p2 = 0.f;
        if (tid < 256 && t + 1 < len) {
            const _Float16* gq = gp + (size_t)(t + 1) * B_ * G_;
            p0 = (float)gq[0]; p1 = (float)gq[256]; p2 = (float)gq[512];
        }

        // ---- dot phase: 16 x (1 broadcast ds_read_b128 + 12 fdot2) ----
        float a0 = 0.f, a1 = 0.f, a2 = 0.f;
        const u32x4* hv4 = (const u32x4*)&hb[cur][half * 128];
#pragma unroll
        for (int p4 = 0; p4 < 16; ++p4) {
            u32x4 hv = hv4[p4];
#pragma unroll
            for (int q = 0; q < 4; ++q) {
                h2v hq = asH(hv[q]);
                a0 = __builtin_amdgcn_fdot2(asH(wq0[p4][q]), hq, a0, false);
                a1 = __builtin_amdgcn_fdot2(asH(wq1[p4][q]), hq, a1, false);
                a2 = __builtin_amdgcn_fdot2(asH(wq2[p4][q]), hq, a2, false);
            }
        }
        part[half][0][j] = a0;
        part[half][1][j] = a1;
        part[half][2][j] = a2;
        __syncthreads();

        // ---- pointwise phase ----
        if (tid < 256) {
            float s0 = part[0][0][j] + part[1][0][j] + bh0;
            float s1 = part[0][1][j] + part[1][1][j] + bh1;
            float s2 = part[0][2][j] + part[1][2][j] + bh2;
            float r = 1.f / (1.f + __expf(-(g0 + s0)));
            float u = 1.f / (1.f + __expf(-(g2 + s2)));
            float carg = g1 + r * s1;
            carg = fminf(fmaxf(carg, -20.f), 20.f);
            float e2 = __expf(2.f * carg);
            float n = (e2 - 1.f) / (e2 + 1.f);
            float hnew = hprev + u * (n - hprev);
            outp[(size_t)t * H_] = hnew;
            hb[cur ^ 1][j] = (_Float16)hnew;
            hprev = hnew;
            g0 = p0; g1 = p1; g2 = p2;
        }
        __syncthreads();
        cur ^= 1;
    }
    if (tid < 256) {
        h_carry[b * 256 + j] = hprev;
        if (t0 + len == T_) hN[b * 256 + j] = hprev;
    }
}

// ---------------------------------------------------------------------------
extern "C" void kernel_launch(void* const* d_in, const int* in_sizes, int n_in,
                              void* d_out, int out_size, void* d_ws, size_t ws_size,
                              hipStream_t stream) {
    const float* x   = (const float*)d_in[0];
    const float* h0  = (const float*)d_in[1];
    const float* Wih = (const float*)d_in[2];
    const float* bih = (const float*)d_in[3];
    const float* Whh = (const float*)d_in[4];
    const float* bhh = (const float*)d_in[5];
    float* out = (float*)d_out;
    float* hN  = out + (size_t)B_ * T_ * H_;

    char* ws = (char*)d_ws;
    float*    h_carry = (float*)ws;                       // 65536 B
    uint32_t* Wprep   = (uint32_t*)(ws + 65536);          // 393216 B
    _Float16* gi      = (_Float16*)(ws + 65536 + 393216);

    const size_t head = 65536 + 393216;
    const size_t per_t = (size_t)B_ * G_ * sizeof(_Float16);  // 98304 B
    size_t avail = (ws_size > head) ? (ws_size - head) : 0;
    int tc = (int)(avail / per_t);
    if (tc > T_) tc = T_;
    if (tc < 1)  tc = 1;
    int nch = (T_ + tc - 1) / tc;
    tc = (T_ + nch - 1) / nch;

    hipLaunchKernelGGL(prep_whh2, dim3(6), dim3(256), 0, stream, Whh, Wprep);
    for (int t0 = 0; t0 < T_; t0 += tc) {
        int len = (T_ - t0 < tc) ? (T_ - t0) : tc;
        hipLaunchKernelGGL(gemm_gi, dim3(len, 2), dim3(256), 0, stream,
                           x, Wih, bih, gi, t0);
        const float* hi = (t0 == 0) ? h0 : h_carry;
        hipLaunchKernelGGL(rec_step, dim3(64), dim3(512), 0, stream,
                           Wprep, bhh, gi, hi, out, hN, h_carry, t0, len);
    }
}